// Round 5
// baseline (224.391 us; speedup 1.0000x reference)
//
#include <hip/hip_runtime.h>

// Sinkhorn (L1 cost), n=2048, d=64, eps=100, 10 frozen-on-converge iters.
// Scaling form: K = exp(-C/eps); z' = z*mu/(z*(K w)+1e-6); w' = w*mu/(w*(K^T z')+1e-6).
// Row kernel fuses the K^T partials (its K rows are L2-hot) -> 2 kernels/iter.
// 23 dispatches total. No atomics (r3 lesson), no coop sync (r2 lesson).

#define N 2048
#define EPS 100.0f
#define INV_EPS 0.01f
#define LOG_MU (-7.6246189861593985f)   // log(1/2048)
#define MU (4.8828125e-4f)              // 1/2048 exact
#define NITER 10
#define TOL 0.1f

__device__ __forceinline__ float wave_sum(float s) {
  #pragma unroll
  for (int off = 32; off > 0; off >>= 1) s += __shfl_down(s, off, 64);
  return s;
}

// ---------------- build: C = L1 pairwise, K = exp(-C/eps); block 0 inits state ----------------
// 1024 blocks, XCD-row-pinned: g=b&7 -> rows [g*256, g*256+256)
__global__ __launch_bounds__(256) void build_c(const float* __restrict__ A,
                                               const float* __restrict__ B,
                                               float* __restrict__ C,
                                               float* __restrict__ K,
                                               float* __restrict__ z_hist,
                                               float* __restrict__ w_hist,
                                               float* __restrict__ u_hist,
                                               int* __restrict__ idx_arr,
                                               int* __restrict__ done_arr) {
  __shared__ float As[64][68];   // transposed [k][i], stride 68
  __shared__ float Bs[64][68];
  const int b = blockIdx.x;
  const int g = b & 7, t = b >> 3;
  const int itl = t >> 5, jt = t & 31;
  const int i0 = (g * 4 + itl) * 64, j0 = jt * 64;
  const int tid = threadIdx.x;
  if (b == 0) {   // init hist slot 0 + chain (consumed only by later kernels)
    #pragma unroll
    for (int q = 0; q < 8; ++q) {
      int r = q * 256 + tid;
      z_hist[r] = 1.f; w_hist[r] = 1.f; u_hist[r] = 0.f;
    }
    if (tid == 0) { idx_arr[0] = 0; done_arr[0] = 0; }
  }
  #pragma unroll
  for (int e = 0; e < 16; ++e) {
    int idx = e * 256 + tid;
    int r = idx >> 6, k = idx & 63;
    As[k][r] = A[(i0 + r) * 64 + k];
    Bs[k][r] = B[(j0 + r) * 64 + k];
  }
  __syncthreads();
  const int ty = tid >> 4, tx = tid & 15;
  float acc[4][4] = {};
  #pragma unroll 8
  for (int k = 0; k < 64; ++k) {
    float4 av = *(const float4*)&As[k][ty * 4];
    float4 bv = *(const float4*)&Bs[k][tx * 4];
    float a[4] = {av.x, av.y, av.z, av.w};
    float c[4] = {bv.x, bv.y, bv.z, bv.w};
    #pragma unroll
    for (int p = 0; p < 4; ++p)
      #pragma unroll
      for (int q = 0; q < 4; ++q)
        acc[p][q] += fabsf(a[p] - c[q]);
  }
  #pragma unroll
  for (int p = 0; p < 4; ++p) {
    size_t off = (size_t)(i0 + ty * 4 + p) * N + j0 + tx * 4;
    float4 o = make_float4(acc[p][0], acc[p][1], acc[p][2], acc[p][3]);
    *(float4*)&C[off] = o;
    float4 e4 = make_float4(__expf(-o.x * INV_EPS), __expf(-o.y * INV_EPS),
                            __expf(-o.z * INV_EPS), __expf(-o.w * INV_EPS));
    // use precise expf for bit-stability headroom
    e4 = make_float4(expf(-o.x * INV_EPS), expf(-o.y * INV_EPS),
                     expf(-o.z * INV_EPS), expf(-o.w * INV_EPS));
    *(float4*)&K[off] = e4;
  }
}

// ---------------- row pass: z', u_new, and column partials ----------------
// 256 blocks x 512 thr; block b: g=b&7, rows g*256 + (b>>3)*8 .. +8 (XCD-local)
__global__ __launch_bounds__(512) void row_pass(const float* __restrict__ K,
    float* __restrict__ z_hist, float* __restrict__ w_hist,
    float* __restrict__ u_hist, float* __restrict__ part,
    const int* __restrict__ idx_arr, int it) {
  __shared__ float wl[N];     // committed w staged in LDS (8 KB)
  __shared__ float zp[8];     // this block's 8 z' values
  const int tid = threadIdx.x;
  const int wv = tid >> 6, lane = tid & 63;
  const int b = blockIdx.x;
  const int rbase = ((b & 7) << 8) + ((b >> 3) << 3);
  const int idx = idx_arr[it];
  const float* __restrict__ wc = w_hist + (size_t)idx * N;
  {  // stage w: 512 threads x 4 = 2048
    float4 w4 = *(const float4*)(wc + tid * 4);
    *(float4*)&wl[tid * 4] = w4;
  }
  __syncthreads();
  // pass 1: rowsum_r = K[r] . w  (wave wv owns row rbase+wv)
  const int r = rbase + wv;
  const float* __restrict__ Krow = K + (size_t)r * N;
  float s = 0.f;
  #pragma unroll
  for (int p = 0; p < 8; ++p) {
    int j = lane * 4 + p * 256;            // contiguous 1KB per wave-instr
    float4 k4 = *(const float4*)(Krow + j);
    float4 w4 = *(const float4*)&wl[j];
    s += k4.x * w4.x + k4.y * w4.y + k4.z * w4.z + k4.w * w4.w;
  }
  s = wave_sum(s);
  if (lane == 0) {
    float zc = z_hist[(size_t)idx * N + r];
    float den = zc * s + 1e-6f;
    float zn = zc * MU / den;
    z_hist[(size_t)(it + 1) * N + r] = zn;
    u_hist[(size_t)(it + 1) * N + r] =
        EPS * (LOG_MU - logf(den)) + u_hist[(size_t)idx * N + r];
    zp[wv] = zn;
  }
  __syncthreads();
  // pass 2: part[b][j] = sum_{rr<8} z'_rr * K[rbase+rr][j]  (K rows L2-hot)
  float z0 = zp[0], z1 = zp[1], z2 = zp[2], z3 = zp[3];
  float z4 = zp[4], z5 = zp[5], z6 = zp[6], z7 = zp[7];
  const int j4 = tid * 4;
  const float* __restrict__ Kb = K + (size_t)rbase * N + j4;
  float4 a0 = *(const float4*)(Kb);
  float4 a1 = *(const float4*)(Kb + N);
  float4 a2 = *(const float4*)(Kb + 2 * N);
  float4 a3 = *(const float4*)(Kb + 3 * N);
  float4 a4 = *(const float4*)(Kb + 4 * N);
  float4 a5 = *(const float4*)(Kb + 5 * N);
  float4 a6 = *(const float4*)(Kb + 6 * N);
  float4 a7 = *(const float4*)(Kb + 7 * N);
  float4 acc;
  acc.x = ((z0*a0.x + z1*a1.x) + (z2*a2.x + z3*a3.x)) + ((z4*a4.x + z5*a5.x) + (z6*a6.x + z7*a7.x));
  acc.y = ((z0*a0.y + z1*a1.y) + (z2*a2.y + z3*a3.y)) + ((z4*a4.y + z5*a5.y) + (z6*a6.y + z7*a7.y));
  acc.z = ((z0*a0.z + z1*a1.z) + (z2*a2.z + z3*a3.z)) + ((z4*a4.z + z5*a5.z) + (z6*a6.z + z7*a7.z));
  acc.w = ((z0*a0.w + z1*a1.w) + (z2*a2.w + z3*a3.w)) + ((z4*a4.w + z5*a5.w) + (z6*a6.w + z7*a7.w));
  *(float4*)&part[(size_t)b * N + j4] = acc;
}

// ---------------- fin: colsum reduce -> w'; block 0: err + done/idx chain ----------------
// 8 blocks x 256 thr; block bk owns j in [bk*256, bk*256+256)
__global__ __launch_bounds__(256) void fin_pass(const float* __restrict__ part,
    float* __restrict__ w_hist, const float* __restrict__ u_hist,
    int* __restrict__ idx_arr, int* __restrict__ done_arr, int it) {
  const int tid = threadIdx.x;
  const int j = blockIdx.x * 256 + tid;
  const int idx = idx_arr[it];
  float cs = 0.f;
  #pragma unroll 8
  for (int p = 0; p < 256; ++p) cs += part[(size_t)p * N + j];
  float wcv = w_hist[(size_t)idx * N + j];
  float den = wcv * cs + 1e-6f;
  w_hist[(size_t)(it + 1) * N + j] = wcv * MU / den;
  if (blockIdx.x == 0) {   // err + chain (uniform branch)
    const float* __restrict__ un = u_hist + (size_t)(it + 1) * N;
    const float* __restrict__ uc = u_hist + (size_t)idx * N;
    float e = 0.f;
    #pragma unroll
    for (int p = 0; p < 2; ++p) {
      int i = tid * 4 + p * 1024;
      float4 a = *(const float4*)(un + i);
      float4 c = *(const float4*)(uc + i);
      e += fabsf(a.x - c.x) + fabsf(a.y - c.y) + fabsf(a.z - c.z) + fabsf(a.w - c.w);
    }
    e = wave_sum(e);
    __shared__ float sh4[4];
    if ((tid & 63) == 0) sh4[tid >> 6] = e;
    __syncthreads();
    if (tid == 0) {
      float err = (sh4[0] + sh4[1]) + (sh4[2] + sh4[3]);
      int dprev = done_arr[it];
      idx_arr[it + 1] = dprev ? idx : (it + 1);
      done_arr[it + 1] = dprev | (err < TOL ? 1 : 0);
    }
  }
}

// ---------------- loss: losspart[b] = sum_{rows of b} z_r * sum_j K*C*w ----------------
// 256 blocks x 512 thr, same row mapping as row_pass
__global__ __launch_bounds__(512) void loss_pass(const float* __restrict__ K,
    const float* __restrict__ C, const float* __restrict__ z_hist,
    const float* __restrict__ w_hist, const int* __restrict__ idx_arr,
    float* __restrict__ losspart) {
  __shared__ float wl[N];
  __shared__ float sh[8];
  const int tid = threadIdx.x;
  const int wv = tid >> 6, lane = tid & 63;
  const int b = blockIdx.x;
  const int rbase = ((b & 7) << 8) + ((b >> 3) << 3);
  const int idx = idx_arr[NITER];
  {
    float4 w4 = *(const float4*)(w_hist + (size_t)idx * N + tid * 4);
    *(float4*)&wl[tid * 4] = w4;
  }
  __syncthreads();
  const int r = rbase + wv;
  const float* __restrict__ Krow = K + (size_t)r * N;
  const float* __restrict__ Crow = C + (size_t)r * N;
  float s = 0.f;
  #pragma unroll
  for (int p = 0; p < 8; ++p) {
    int j = lane * 4 + p * 256;
    float4 k4 = *(const float4*)(Krow + j);
    float4 c4 = *(const float4*)(Crow + j);
    float4 w4 = *(const float4*)&wl[j];
    s += k4.x * c4.x * w4.x + k4.y * c4.y * w4.y
       + k4.z * c4.z * w4.z + k4.w * c4.w * w4.w;
  }
  s = wave_sum(s);
  if (lane == 0) sh[wv] = s * z_hist[(size_t)idx * N + r];
  __syncthreads();
  if (tid == 0)
    losspart[b] = ((sh[0] + sh[1]) + (sh[2] + sh[3]))
                + ((sh[4] + sh[5]) + (sh[6] + sh[7]));
}

__global__ __launch_bounds__(256) void loss_reduce(const float* __restrict__ losspart,
                                                   float* __restrict__ out) {
  float s = losspart[threadIdx.x];
  s = wave_sum(s);
  __shared__ float sh4[4];
  if ((threadIdx.x & 63) == 0) sh4[threadIdx.x >> 6] = s;
  __syncthreads();
  if (threadIdx.x == 0) out[0] = (sh4[0] + sh4[1]) + (sh4[2] + sh4[3]);
}

extern "C" void kernel_launch(void* const* d_in, const int* in_sizes, int n_in,
                              void* d_out, int out_size, void* d_ws, size_t ws_size,
                              hipStream_t stream) {
  const float* A = (const float*)d_in[0];
  const float* B = (const float*)d_in[1];
  float* out = (float*)d_out;

  char* base = (char*)d_ws;
  float* K        = (float*)base;                                // 16 MiB
  float* C        = (float*)(base + (size_t)N * N * 4);          // 16 MiB
  float* z_hist   = (float*)(base + (size_t)2 * N * N * 4);      // [11][N]
  float* w_hist   = z_hist + (size_t)(NITER + 1) * N;
  float* u_hist   = w_hist + (size_t)(NITER + 1) * N;
  float* part     = u_hist + (size_t)(NITER + 1) * N;            // [256][N] = 2 MiB
  float* losspart = part + (size_t)256 * N;                      // [256]
  int*   idx_arr  = (int*)(losspart + 256);                      // [11]
  int*   done_arr = idx_arr + (NITER + 1);                       // [11]

  build_c<<<1024, 256, 0, stream>>>(A, B, C, K, z_hist, w_hist, u_hist,
                                    idx_arr, done_arr);
  for (int it = 0; it < NITER; ++it) {
    row_pass<<<256, 512, 0, stream>>>(K, z_hist, w_hist, u_hist, part, idx_arr, it);
    fin_pass<<<8, 256, 0, stream>>>(part, w_hist, u_hist, idx_arr, done_arr, it);
  }
  loss_pass<<<256, 512, 0, stream>>>(K, C, z_hist, w_hist, idx_arr, losspart);
  loss_reduce<<<1, 256, 0, stream>>>(losspart, out);
}

// Round 6
// 111.320 us; speedup vs baseline: 2.0157x; 2.0157x over previous
//
#include <hip/hip_runtime.h>

// Sinkhorn (L1 cost), n=2048, d=64, eps=100, 10 frozen-on-converge iters.
// Scaling form with BOTH K and K^T materialized (XCD-pinned slices, 2 MiB/XCD
// each -> L2-resident). Iteration = two coalesced row-matvecs, no partials.
// C never stored: loss uses C = -eps*log(K). 24 dispatches, no atomics
// (r3 lesson), no coop sync (r2 lesson), no tiny-grid latency reducers
// (r5 lesson: 8-block scatter reduce cost ~9us/iter).

#define N 2048
#define EPS 100.0f
#define INV_EPS 0.01f
#define LOG_MU (-7.6246189861593985f)   // log(1/2048)
#define MU (4.8828125e-4f)              // 1/2048 exact
#define NITER 10
#define TOL 0.1f

__device__ __forceinline__ float wave_sum(float s) {
  #pragma unroll
  for (int off = 32; off > 0; off >>= 1) s += __shfl_down(s, off, 64);
  return s;
}

// ---------------- build: K[i][j] = exp(-sum_k |A[i][k]-B[j][k]| / eps) ----------------
// 1024 blocks, XCD-row-pinned: g=b&7 -> rows [g*256, g*256+256). 4x4 register tile.
__global__ __launch_bounds__(256) void build_k(const float* __restrict__ A,
                                               const float* __restrict__ B,
                                               float* __restrict__ K,
                                               float* __restrict__ z_hist,
                                               float* __restrict__ w_hist,
                                               float* __restrict__ u_hist,
                                               int* __restrict__ idx_arr,
                                               int* __restrict__ done_arr) {
  __shared__ float As[64][68];   // transposed [k][i], stride 68
  __shared__ float Bs[64][68];
  const int b = blockIdx.x;
  const int g = b & 7, t = b >> 3;
  const int itl = t >> 5, jt = t & 31;
  const int i0 = (g * 4 + itl) * 64, j0 = jt * 64;
  const int tid = threadIdx.x;
  if (b == 0) {   // init hist slot 0 + chain scalars
    #pragma unroll
    for (int q = 0; q < 8; ++q) {
      int r = q * 256 + tid;
      z_hist[r] = 1.f; w_hist[r] = 1.f; u_hist[r] = 0.f;
    }
    if (tid == 0) { idx_arr[0] = 0; done_arr[0] = 0; }
  }
  #pragma unroll
  for (int e = 0; e < 16; ++e) {
    int idx = e * 256 + tid;
    int r = idx >> 6, k = idx & 63;
    As[k][r] = A[(i0 + r) * 64 + k];
    Bs[k][r] = B[(j0 + r) * 64 + k];
  }
  __syncthreads();
  const int ty = tid >> 4, tx = tid & 15;
  float acc[4][4] = {};
  #pragma unroll 8
  for (int k = 0; k < 64; ++k) {
    float4 av = *(const float4*)&As[k][ty * 4];
    float4 bv = *(const float4*)&Bs[k][tx * 4];
    float a[4] = {av.x, av.y, av.z, av.w};
    float c[4] = {bv.x, bv.y, bv.z, bv.w};
    #pragma unroll
    for (int p = 0; p < 4; ++p)
      #pragma unroll
      for (int q = 0; q < 4; ++q)
        acc[p][q] += fabsf(a[p] - c[q]);
  }
  #pragma unroll
  for (int p = 0; p < 4; ++p) {
    float4 e4 = make_float4(expf(-acc[p][0] * INV_EPS), expf(-acc[p][1] * INV_EPS),
                            expf(-acc[p][2] * INV_EPS), expf(-acc[p][3] * INV_EPS));
    *(float4*)&K[(size_t)(i0 + ty * 4 + p) * N + j0 + tx * 4] = e4;
  }
}

// ---------------- one-time transpose: KT[j][i] = K[i][j], pinned by j-group ----------------
// 1024 blocks: g=b&7 -> j-rows [g*256, ...); writer XCD == later reader XCD.
__global__ __launch_bounds__(256) void kt_pass(const float* __restrict__ K,
                                               float* __restrict__ KT) {
  __shared__ float tile[64][65];
  const int b = blockIdx.x;
  const int g = b & 7, t = b >> 3;
  const int j0 = (g * 4 + (t >> 5)) * 64;
  const int i0 = (t & 31) * 64;
  const int tid = threadIdx.x;
  const int r = tid >> 4, c4 = (tid & 15) * 4;
  #pragma unroll
  for (int rr = 0; rr < 64; rr += 16) {
    float4 k4 = *(const float4*)&K[(size_t)(i0 + rr + r) * N + j0 + c4];
    tile[rr + r][c4]     = k4.x; tile[rr + r][c4 + 1] = k4.y;
    tile[rr + r][c4 + 2] = k4.z; tile[rr + r][c4 + 3] = k4.w;
  }
  __syncthreads();
  #pragma unroll
  for (int jr = 0; jr < 64; jr += 16) {
    int j = jr + r;
    float4 o = make_float4(tile[c4][j], tile[c4 + 1][j],
                           tile[c4 + 2][j], tile[c4 + 3][j]);
    *(float4*)&KT[(size_t)(j0 + j) * N + i0 + c4] = o;
  }
}

// ---------------- row matvec: z' and u_new ----------------
// 256 blocks x 512 thr; wave wv owns row rbase+wv (XCD-local K rows)
__global__ __launch_bounds__(512) void rowz(const float* __restrict__ K,
    float* __restrict__ z_hist, const float* __restrict__ w_hist,
    float* __restrict__ u_hist, const int* __restrict__ idx_arr, int it) {
  __shared__ float wl[N];
  const int tid = threadIdx.x, wv = tid >> 6, lane = tid & 63;
  const int b = blockIdx.x;
  const int rbase = ((b & 7) << 8) + ((b >> 3) << 3);
  const int idx = idx_arr[it];
  *(float4*)&wl[tid * 4] = *(const float4*)(w_hist + (size_t)idx * N + tid * 4);
  __syncthreads();
  const int r = rbase + wv;
  const float* __restrict__ Krow = K + (size_t)r * N;
  float s = 0.f;
  #pragma unroll
  for (int p = 0; p < 8; ++p) {
    int j = lane * 4 + p * 256;         // wave covers contiguous 1 KB per step
    float4 k4 = *(const float4*)(Krow + j);
    float4 w4 = *(const float4*)&wl[j];
    s += k4.x * w4.x + k4.y * w4.y + k4.z * w4.z + k4.w * w4.w;
  }
  s = wave_sum(s);
  if (lane == 0) {
    float zc = z_hist[(size_t)idx * N + r];
    float den = zc * s + 1e-6f;          // == rowsum(exp(M)) + 1e-6 of reference
    z_hist[(size_t)(it + 1) * N + r] = zc * MU / den;
    u_hist[(size_t)(it + 1) * N + r] =
        EPS * (LOG_MU - logf(den)) + u_hist[(size_t)idx * N + r];
  }
}

// ---------------- col matvec: w'; block 0 also runs err/done/idx chain ----------------
__global__ __launch_bounds__(512) void colw(const float* __restrict__ KT,
    const float* __restrict__ z_hist, float* __restrict__ w_hist,
    const float* __restrict__ u_hist, int* __restrict__ idx_arr,
    int* __restrict__ done_arr, int it) {
  __shared__ float zl[N];
  const int tid = threadIdx.x, wv = tid >> 6, lane = tid & 63;
  const int b = blockIdx.x;
  const int jbase = ((b & 7) << 8) + ((b >> 3) << 3);
  const int idx = idx_arr[it];
  *(float4*)&zl[tid * 4] = *(const float4*)(z_hist + (size_t)(it + 1) * N + tid * 4);
  __syncthreads();
  const int j = jbase + wv;
  const float* __restrict__ Kc = KT + (size_t)j * N;
  float s = 0.f;
  #pragma unroll
  for (int p = 0; p < 8; ++p) {
    int i = lane * 4 + p * 256;
    float4 k4 = *(const float4*)(Kc + i);
    float4 z4 = *(const float4*)&zl[i];
    s += k4.x * z4.x + k4.y * z4.y + k4.z * z4.z + k4.w * z4.w;
  }
  s = wave_sum(s);
  if (lane == 0) {
    float wc = w_hist[(size_t)idx * N + j];
    float den = wc * s + 1e-6f;
    w_hist[(size_t)(it + 1) * N + j] = wc * MU / den;
  }
  if (b == 0) {   // block-uniform branch: err in u-domain + convergence chain
    const float* __restrict__ un = u_hist + (size_t)(it + 1) * N;
    const float* __restrict__ uc = u_hist + (size_t)idx * N;
    float4 a = *(const float4*)(un + tid * 4);
    float4 c = *(const float4*)(uc + tid * 4);
    float e = fabsf(a.x - c.x) + fabsf(a.y - c.y)
            + fabsf(a.z - c.z) + fabsf(a.w - c.w);
    e = wave_sum(e);
    __shared__ float sh8[8];
    if (lane == 0) sh8[wv] = e;
    __syncthreads();
    if (tid == 0) {
      float err = ((sh8[0] + sh8[1]) + (sh8[2] + sh8[3]))
                + ((sh8[4] + sh8[5]) + (sh8[6] + sh8[7]));
      int dprev = done_arr[it];
      idx_arr[it + 1] = dprev ? idx : (it + 1);
      done_arr[it + 1] = dprev | (err < TOL ? 1 : 0);
    }
  }
}

// ---------------- loss: sum_i z_i sum_j K_ij * w_j * (-eps*log(K_ij)) ----------------
__global__ __launch_bounds__(512) void loss_pass(const float* __restrict__ K,
    const float* __restrict__ z_hist, const float* __restrict__ w_hist,
    const int* __restrict__ idx_arr, float* __restrict__ losspart) {
  __shared__ float wl[N];
  __shared__ float sh8[8];
  const int tid = threadIdx.x, wv = tid >> 6, lane = tid & 63;
  const int b = blockIdx.x;
  const int rbase = ((b & 7) << 8) + ((b >> 3) << 3);
  const int idx = idx_arr[NITER];
  *(float4*)&wl[tid * 4] = *(const float4*)(w_hist + (size_t)idx * N + tid * 4);
  __syncthreads();
  const int r = rbase + wv;
  const float* __restrict__ Krow = K + (size_t)r * N;
  float s = 0.f;
  #pragma unroll
  for (int p = 0; p < 8; ++p) {
    int j = lane * 4 + p * 256;
    float4 k4 = *(const float4*)(Krow + j);
    float4 w4 = *(const float4*)&wl[j];
    s += k4.x * w4.x * (-EPS * logf(k4.x)) + k4.y * w4.y * (-EPS * logf(k4.y))
       + k4.z * w4.z * (-EPS * logf(k4.z)) + k4.w * w4.w * (-EPS * logf(k4.w));
  }
  s = wave_sum(s);
  if (lane == 0) sh8[wv] = s * z_hist[(size_t)idx * N + r];
  __syncthreads();
  if (tid == 0)
    losspart[b] = ((sh8[0] + sh8[1]) + (sh8[2] + sh8[3]))
                + ((sh8[4] + sh8[5]) + (sh8[6] + sh8[7]));
}

__global__ __launch_bounds__(256) void loss_reduce(const float* __restrict__ losspart,
                                                   float* __restrict__ out) {
  float s = losspart[threadIdx.x];
  s = wave_sum(s);
  __shared__ float sh4[4];
  if ((threadIdx.x & 63) == 0) sh4[threadIdx.x >> 6] = s;
  __syncthreads();
  if (threadIdx.x == 0) out[0] = (sh4[0] + sh4[1]) + (sh4[2] + sh4[3]);
}

extern "C" void kernel_launch(void* const* d_in, const int* in_sizes, int n_in,
                              void* d_out, int out_size, void* d_ws, size_t ws_size,
                              hipStream_t stream) {
  const float* A = (const float*)d_in[0];
  const float* B = (const float*)d_in[1];
  float* out = (float*)d_out;

  char* base = (char*)d_ws;
  float* K        = (float*)base;                                // 16 MiB
  float* KT       = (float*)(base + (size_t)N * N * 4);          // 16 MiB
  float* z_hist   = (float*)(base + (size_t)2 * N * N * 4);      // [11][N]
  float* w_hist   = z_hist + (size_t)(NITER + 1) * N;
  float* u_hist   = w_hist + (size_t)(NITER + 1) * N;
  float* losspart = u_hist + (size_t)(NITER + 1) * N;            // [256]
  int*   idx_arr  = (int*)(losspart + 256);                      // [11]
  int*   done_arr = idx_arr + (NITER + 1);                       // [11]

  build_k<<<1024, 256, 0, stream>>>(A, B, K, z_hist, w_hist, u_hist,
                                    idx_arr, done_arr);
  kt_pass<<<1024, 256, 0, stream>>>(K, KT);
  for (int it = 0; it < NITER; ++it) {
    rowz<<<256, 512, 0, stream>>>(K, z_hist, w_hist, u_hist, idx_arr, it);
    colw<<<256, 512, 0, stream>>>(KT, z_hist, w_hist, u_hist, idx_arr,
                                  done_arr, it);
  }
  loss_pass<<<256, 512, 0, stream>>>(K, z_hist, w_hist, idx_arr, losspart);
  loss_reduce<<<1, 256, 0, stream>>>(losspart, out);
}

// Round 7
// 103.203 us; speedup vs baseline: 2.1743x; 1.0787x over previous
//
#include <hip/hip_runtime.h>

// Sinkhorn (L1 cost), n=2048, d=64, eps=100, 10 frozen-on-converge iters.
// Scaling form, K and K^T both materialized; transpose fused into build via
// LDS round-trip (r6 lesson: separate kt_pass cost ~6us incl dispatch).
// 23 dispatches: build + 10x(rowz,colw) + loss + reduce. No atomics (r3),
// no coop sync (r2), no tiny-grid latency reducers (r5).

#define N 2048
#define EPS 100.0f
#define INV_EPS 0.01f
#define LOG_MU (-7.6246189861593985f)   // log(1/2048)
#define MU (4.8828125e-4f)              // 1/2048 exact
#define NITER 10
#define TOL 0.1f

__device__ __forceinline__ float wave_sum(float s) {
  #pragma unroll
  for (int off = 32; off > 0; off >>= 1) s += __shfl_down(s, off, 64);
  return s;
}

// ---------------- build: K = exp(-L1/eps), KT = K^T (fused), init state ----------------
// 1024 blocks, K XCD-row-pinned: g=b&7 -> i-rows [g*256, g*256+256).
__global__ __launch_bounds__(256) void build_k(const float* __restrict__ A,
                                               const float* __restrict__ B,
                                               float* __restrict__ K,
                                               float* __restrict__ KT,
                                               float* __restrict__ z_hist,
                                               float* __restrict__ w_hist,
                                               float* __restrict__ u_hist,
                                               int* __restrict__ idx_arr,
                                               int* __restrict__ done_arr) {
  __shared__ float As[64][68];   // inputs transposed [k][i], stride 68
  __shared__ float Bs[64][68];
  __shared__ float T[64][68];    // K-tile staging for transposed write
  const int b = blockIdx.x;
  const int g = b & 7, t = b >> 3;
  const int itl = t >> 5, jt = t & 31;
  const int i0 = (g * 4 + itl) * 64, j0 = jt * 64;
  const int tid = threadIdx.x;
  if (b == 0) {   // init hist slot 0 + chain scalars
    #pragma unroll
    for (int q = 0; q < 8; ++q) {
      int r = q * 256 + tid;
      z_hist[r] = 1.f; w_hist[r] = 1.f; u_hist[r] = 0.f;
    }
    if (tid == 0) { idx_arr[0] = 0; done_arr[0] = 0; }
  }
  #pragma unroll
  for (int e = 0; e < 16; ++e) {
    int idx = e * 256 + tid;
    int r = idx >> 6, k = idx & 63;
    As[k][r] = A[(i0 + r) * 64 + k];
    Bs[k][r] = B[(j0 + r) * 64 + k];
  }
  __syncthreads();
  const int ty = tid >> 4, tx = tid & 15;
  float acc[4][4] = {};
  #pragma unroll 8
  for (int k = 0; k < 64; ++k) {
    float4 av = *(const float4*)&As[k][ty * 4];
    float4 bv = *(const float4*)&Bs[k][tx * 4];
    float a[4] = {av.x, av.y, av.z, av.w};
    float c[4] = {bv.x, bv.y, bv.z, bv.w};
    #pragma unroll
    for (int p = 0; p < 4; ++p)
      #pragma unroll
      for (int q = 0; q < 4; ++q)
        acc[p][q] += fabsf(a[p] - c[q]);
  }
  #pragma unroll
  for (int p = 0; p < 4; ++p) {
    float4 e4 = make_float4(expf(-acc[p][0] * INV_EPS), expf(-acc[p][1] * INV_EPS),
                            expf(-acc[p][2] * INV_EPS), expf(-acc[p][3] * INV_EPS));
    *(float4*)&K[(size_t)(i0 + ty * 4 + p) * N + j0 + tx * 4] = e4;
    // stage for transposed write: T[i_local][j_local]
    T[ty * 4 + p][tx * 4 + 0] = e4.x;
    T[ty * 4 + p][tx * 4 + 1] = e4.y;
    T[ty * 4 + p][tx * 4 + 2] = e4.z;
    T[ty * 4 + p][tx * 4 + 3] = e4.w;
  }
  __syncthreads();
  // KT write: thread (ty,tx) -> KT rows j0+ty*4+p, cols i0+tx*4 (coalesced)
  #pragma unroll
  for (int p = 0; p < 4; ++p) {
    int jl = ty * 4 + p;
    float4 o = make_float4(T[tx * 4 + 0][jl], T[tx * 4 + 1][jl],
                           T[tx * 4 + 2][jl], T[tx * 4 + 3][jl]);
    *(float4*)&KT[(size_t)(j0 + jl) * N + i0 + tx * 4] = o;
  }
}

// ---------------- row matvec: z' and u_new ----------------
// 512 blocks x 256 thr; wave wv (0..3) owns row rbase+wv (XCD-local K rows)
__global__ __launch_bounds__(256) void rowz(const float* __restrict__ K,
    float* __restrict__ z_hist, const float* __restrict__ w_hist,
    float* __restrict__ u_hist, const int* __restrict__ idx_arr, int it) {
  __shared__ float wl[N];
  const int tid = threadIdx.x, wv = tid >> 6, lane = tid & 63;
  const int b = blockIdx.x;
  const int rbase = ((b & 7) << 8) + ((b >> 3) << 2);
  const int idx = idx_arr[it];
  {
    const float* __restrict__ wc = w_hist + (size_t)idx * N;
    *(float4*)&wl[tid * 8]     = *(const float4*)(wc + tid * 8);
    *(float4*)&wl[tid * 8 + 4] = *(const float4*)(wc + tid * 8 + 4);
  }
  __syncthreads();
  const int r = rbase + wv;
  const float* __restrict__ Krow = K + (size_t)r * N;
  float s = 0.f;
  #pragma unroll
  for (int p = 0; p < 8; ++p) {
    int j = lane * 4 + p * 256;         // wave covers contiguous 1 KB per step
    float4 k4 = *(const float4*)(Krow + j);
    float4 w4 = *(const float4*)&wl[j];
    s += k4.x * w4.x + k4.y * w4.y + k4.z * w4.z + k4.w * w4.w;
  }
  s = wave_sum(s);
  if (lane == 0) {
    float zc = z_hist[(size_t)idx * N + r];
    float den = zc * s + 1e-6f;          // == rowsum(exp(M)) + 1e-6 of reference
    z_hist[(size_t)(it + 1) * N + r] = zc * MU / den;
    u_hist[(size_t)(it + 1) * N + r] =
        EPS * (LOG_MU - logf(den)) + u_hist[(size_t)idx * N + r];
  }
}

// ---------------- col matvec: w'; block 0 also runs err/done/idx chain ----------------
// 512 blocks x 256 thr; wave wv owns column jbase+wv (XCD-local KT rows)
__global__ __launch_bounds__(256) void colw(const float* __restrict__ KT,
    const float* __restrict__ z_hist, float* __restrict__ w_hist,
    const float* __restrict__ u_hist, int* __restrict__ idx_arr,
    int* __restrict__ done_arr, int it) {
  __shared__ float zl[N];
  const int tid = threadIdx.x, wv = tid >> 6, lane = tid & 63;
  const int b = blockIdx.x;
  const int jbase = ((b & 7) << 8) + ((b >> 3) << 2);
  const int idx = idx_arr[it];
  {
    const float* __restrict__ zn = z_hist + (size_t)(it + 1) * N;
    *(float4*)&zl[tid * 8]     = *(const float4*)(zn + tid * 8);
    *(float4*)&zl[tid * 8 + 4] = *(const float4*)(zn + tid * 8 + 4);
  }
  __syncthreads();
  const int j = jbase + wv;
  const float* __restrict__ Kc = KT + (size_t)j * N;
  float s = 0.f;
  #pragma unroll
  for (int p = 0; p < 8; ++p) {
    int i = lane * 4 + p * 256;
    float4 k4 = *(const float4*)(Kc + i);
    float4 z4 = *(const float4*)&zl[i];
    s += k4.x * z4.x + k4.y * z4.y + k4.z * z4.z + k4.w * z4.w;
  }
  s = wave_sum(s);
  if (lane == 0) {
    float wc = w_hist[(size_t)idx * N + j];
    float den = wc * s + 1e-6f;
    w_hist[(size_t)(it + 1) * N + j] = wc * MU / den;
  }
  if (b == 0) {   // block-uniform branch: err in u-domain + convergence chain
    const float* __restrict__ un = u_hist + (size_t)(it + 1) * N;
    const float* __restrict__ uc = u_hist + (size_t)idx * N;
    float e = 0.f;
    #pragma unroll
    for (int p = 0; p < 2; ++p) {
      int i = tid * 4 + p * 1024;
      float4 a = *(const float4*)(un + i);
      float4 c = *(const float4*)(uc + i);
      e += fabsf(a.x - c.x) + fabsf(a.y - c.y)
         + fabsf(a.z - c.z) + fabsf(a.w - c.w);
    }
    e = wave_sum(e);
    __shared__ float sh4[4];
    if (lane == 0) sh4[wv] = e;
    __syncthreads();
    if (tid == 0) {
      float err = (sh4[0] + sh4[1]) + (sh4[2] + sh4[3]);
      int dprev = done_arr[it];
      idx_arr[it + 1] = dprev ? idx : (it + 1);
      done_arr[it + 1] = dprev | (err < TOL ? 1 : 0);
    }
  }
}

// ---------------- loss: sum_i z_i sum_j K_ij * w_j * (-eps*log(K_ij)) ----------------
__global__ __launch_bounds__(512) void loss_pass(const float* __restrict__ K,
    const float* __restrict__ z_hist, const float* __restrict__ w_hist,
    const int* __restrict__ idx_arr, float* __restrict__ losspart) {
  __shared__ float wl[N];
  __shared__ float sh8[8];
  const int tid = threadIdx.x, wv = tid >> 6, lane = tid & 63;
  const int b = blockIdx.x;
  const int rbase = ((b & 7) << 8) + ((b >> 3) << 3);
  const int idx = idx_arr[NITER];
  *(float4*)&wl[tid * 4] = *(const float4*)(w_hist + (size_t)idx * N + tid * 4);
  __syncthreads();
  const int r = rbase + wv;
  const float* __restrict__ Krow = K + (size_t)r * N;
  float s = 0.f;
  #pragma unroll
  for (int p = 0; p < 8; ++p) {
    int j = lane * 4 + p * 256;
    float4 k4 = *(const float4*)(Krow + j);
    float4 w4 = *(const float4*)&wl[j];
    s += k4.x * w4.x * (-EPS * logf(k4.x)) + k4.y * w4.y * (-EPS * logf(k4.y))
       + k4.z * w4.z * (-EPS * logf(k4.z)) + k4.w * w4.w * (-EPS * logf(k4.w));
  }
  s = wave_sum(s);
  if (lane == 0) sh8[wv] = s * z_hist[(size_t)idx * N + r];
  __syncthreads();
  if (tid == 0)
    losspart[b] = ((sh8[0] + sh8[1]) + (sh8[2] + sh8[3]))
                + ((sh8[4] + sh8[5]) + (sh8[6] + sh8[7]));
}

__global__ __launch_bounds__(256) void loss_reduce(const float* __restrict__ losspart,
                                                   float* __restrict__ out) {
  float s = losspart[threadIdx.x];
  s = wave_sum(s);
  __shared__ float sh4[4];
  if ((threadIdx.x & 63) == 0) sh4[threadIdx.x >> 6] = s;
  __syncthreads();
  if (threadIdx.x == 0) out[0] = (sh4[0] + sh4[1]) + (sh4[2] + sh4[3]);
}

extern "C" void kernel_launch(void* const* d_in, const int* in_sizes, int n_in,
                              void* d_out, int out_size, void* d_ws, size_t ws_size,
                              hipStream_t stream) {
  const float* A = (const float*)d_in[0];
  const float* B = (const float*)d_in[1];
  float* out = (float*)d_out;

  char* base = (char*)d_ws;
  float* K        = (float*)base;                                // 16 MiB
  float* KT       = (float*)(base + (size_t)N * N * 4);          // 16 MiB
  float* z_hist   = (float*)(base + (size_t)2 * N * N * 4);      // [11][N]
  float* w_hist   = z_hist + (size_t)(NITER + 1) * N;
  float* u_hist   = w_hist + (size_t)(NITER + 1) * N;
  float* losspart = u_hist + (size_t)(NITER + 1) * N;            // [256]
  int*   idx_arr  = (int*)(losspart + 256);                      // [11]
  int*   done_arr = idx_arr + (NITER + 1);                       // [11]

  build_k<<<1024, 256, 0, stream>>>(A, B, K, KT, z_hist, w_hist, u_hist,
                                    idx_arr, done_arr);
  for (int it = 0; it < NITER; ++it) {
    rowz<<<512, 256, 0, stream>>>(K, z_hist, w_hist, u_hist, idx_arr, it);
    colw<<<512, 256, 0, stream>>>(KT, z_hist, w_hist, u_hist, idx_arr,
                                  done_arr, it);
  }
  loss_pass<<<256, 512, 0, stream>>>(K, z_hist, w_hist, idx_arr, losspart);
  loss_reduce<<<1, 256, 0, stream>>>(losspart, out);
}

// Round 8
// 73.140 us; speedup vs baseline: 3.0680x; 1.4110x over previous
//
#include <hip/hip_runtime.h>

// Sinkhorn (L1 cost), n=2048, d=64, eps=100, 10 frozen-on-converge iters.
// Scaling form; K and K^T in FP16 (8 MiB each, L2-resident, rel err 5e-4 ->
// loss err ~0.05 vs threshold 1.44). Transpose fused into build (r7).
// Early-exit once converged: skipped slots are never referenced by idx chain.
// 23 dispatches: build + 10x(rowz,colw) + loss + reduce. No atomics (r3),
// no coop sync (r2), no tiny-grid latency reducers (r5).

#define N 2048
#define EPS 100.0f
#define INV_EPS 0.01f
#define LOG_MU (-7.6246189861593985f)   // log(1/2048)
#define MU (4.8828125e-4f)              // 1/2048 exact
#define NITER 10
#define TOL 0.1f

typedef _Float16 h16x8 __attribute__((ext_vector_type(8)));
typedef _Float16 h16x4 __attribute__((ext_vector_type(4)));

__device__ __forceinline__ float wave_sum(float s) {
  #pragma unroll
  for (int off = 32; off > 0; off >>= 1) s += __shfl_down(s, off, 64);
  return s;
}

// ---------------- build: K = exp(-L1/eps) fp16, KT fused, init state ----------------
// 1024 blocks, K XCD-row-pinned: g=b&7 -> i-rows [g*256, g*256+256).
__global__ __launch_bounds__(256) void build_k(const float* __restrict__ A,
                                               const float* __restrict__ B,
                                               _Float16* __restrict__ K,
                                               _Float16* __restrict__ KT,
                                               float* __restrict__ z_hist,
                                               float* __restrict__ w_hist,
                                               float* __restrict__ u_hist,
                                               int* __restrict__ idx_arr,
                                               int* __restrict__ done_arr) {
  __shared__ float As[64][68];   // inputs transposed [k][i], stride 68
  __shared__ float Bs[64][68];
  __shared__ float T[64][68];    // K-tile staging for transposed write
  const int b = blockIdx.x;
  const int g = b & 7, t = b >> 3;
  const int itl = t >> 5, jt = t & 31;
  const int i0 = (g * 4 + itl) * 64, j0 = jt * 64;
  const int tid = threadIdx.x;
  if (b == 0) {   // init hist slot 0 + chain scalars
    #pragma unroll
    for (int q = 0; q < 8; ++q) {
      int r = q * 256 + tid;
      z_hist[r] = 1.f; w_hist[r] = 1.f; u_hist[r] = 0.f;
    }
    if (tid == 0) { idx_arr[0] = 0; done_arr[0] = 0; }
  }
  #pragma unroll
  for (int e = 0; e < 16; ++e) {
    int idx = e * 256 + tid;
    int r = idx >> 6, k = idx & 63;
    As[k][r] = A[(i0 + r) * 64 + k];
    Bs[k][r] = B[(j0 + r) * 64 + k];
  }
  __syncthreads();
  const int ty = tid >> 4, tx = tid & 15;
  float acc[4][4] = {};
  #pragma unroll 8
  for (int k = 0; k < 64; ++k) {
    float4 av = *(const float4*)&As[k][ty * 4];
    float4 bv = *(const float4*)&Bs[k][tx * 4];
    float a[4] = {av.x, av.y, av.z, av.w};
    float c[4] = {bv.x, bv.y, bv.z, bv.w};
    #pragma unroll
    for (int p = 0; p < 4; ++p)
      #pragma unroll
      for (int q = 0; q < 4; ++q)
        acc[p][q] += fabsf(a[p] - c[q]);   // sub + add-with-abs-modifier
  }
  #pragma unroll
  for (int p = 0; p < 4; ++p) {
    float4 e4 = make_float4(expf(-acc[p][0] * INV_EPS), expf(-acc[p][1] * INV_EPS),
                            expf(-acc[p][2] * INV_EPS), expf(-acc[p][3] * INV_EPS));
    h16x4 kv;
    kv[0] = (_Float16)e4.x; kv[1] = (_Float16)e4.y;
    kv[2] = (_Float16)e4.z; kv[3] = (_Float16)e4.w;
    *(h16x4*)&K[(size_t)(i0 + ty * 4 + p) * N + j0 + tx * 4] = kv;
    T[ty * 4 + p][tx * 4 + 0] = e4.x;
    T[ty * 4 + p][tx * 4 + 1] = e4.y;
    T[ty * 4 + p][tx * 4 + 2] = e4.z;
    T[ty * 4 + p][tx * 4 + 3] = e4.w;
  }
  __syncthreads();
  // KT write: thread (ty,tx) -> KT rows j0+ty*4+p, cols i0+tx*4 (coalesced 8B)
  #pragma unroll
  for (int p = 0; p < 4; ++p) {
    int jl = ty * 4 + p;
    h16x4 o;
    o[0] = (_Float16)T[tx * 4 + 0][jl]; o[1] = (_Float16)T[tx * 4 + 1][jl];
    o[2] = (_Float16)T[tx * 4 + 2][jl]; o[3] = (_Float16)T[tx * 4 + 3][jl];
    *(h16x4*)&KT[(size_t)(j0 + jl) * N + i0 + tx * 4] = o;
  }
}

// ---------------- row matvec: z' and u_new (skipped once converged) ----------------
// 512 blocks x 256 thr; wave wv (0..3) owns row rbase+wv (XCD-local K rows)
__global__ __launch_bounds__(256) void rowz(const _Float16* __restrict__ K,
    float* __restrict__ z_hist, const float* __restrict__ w_hist,
    float* __restrict__ u_hist, const int* __restrict__ idx_arr,
    const int* __restrict__ done_arr, int it) {
  if (done_arr[it]) return;       // slot it+1 never referenced by idx chain
  __shared__ float wl[N];
  const int tid = threadIdx.x, wv = tid >> 6, lane = tid & 63;
  const int b = blockIdx.x;
  const int rbase = ((b & 7) << 8) + ((b >> 3) << 2);
  const int idx = idx_arr[it];
  {
    const float* __restrict__ wc = w_hist + (size_t)idx * N;
    *(float4*)&wl[tid * 8]     = *(const float4*)(wc + tid * 8);
    *(float4*)&wl[tid * 8 + 4] = *(const float4*)(wc + tid * 8 + 4);
  }
  __syncthreads();
  const int r = rbase + wv;
  const _Float16* __restrict__ Krow = K + (size_t)r * N;
  float s = 0.f;
  #pragma unroll
  for (int p = 0; p < 4; ++p) {
    int j = lane * 8 + p * 512;          // wave covers contiguous 1 KB per step
    h16x8 k8 = *(const h16x8*)(Krow + j);
    float4 wa = *(const float4*)&wl[j];
    float4 wb = *(const float4*)&wl[j + 4];
    s += (float)k8[0] * wa.x + (float)k8[1] * wa.y
       + (float)k8[2] * wa.z + (float)k8[3] * wa.w
       + (float)k8[4] * wb.x + (float)k8[5] * wb.y
       + (float)k8[6] * wb.z + (float)k8[7] * wb.w;
  }
  s = wave_sum(s);
  if (lane == 0) {
    float zc = z_hist[(size_t)idx * N + r];
    float den = zc * s + 1e-6f;          // == rowsum(exp(M)) + 1e-6 of reference
    z_hist[(size_t)(it + 1) * N + r] = zc * MU / den;
    u_hist[(size_t)(it + 1) * N + r] =
        EPS * (LOG_MU - logf(den)) + u_hist[(size_t)idx * N + r];
  }
}

// ---------------- col matvec: w'; block 0 runs err/done/idx chain ----------------
// 512 blocks x 256 thr; wave wv owns column jbase+wv (XCD-local KT rows)
__global__ __launch_bounds__(256) void colw(const _Float16* __restrict__ KT,
    const float* __restrict__ z_hist, float* __restrict__ w_hist,
    const float* __restrict__ u_hist, int* __restrict__ idx_arr,
    int* __restrict__ done_arr, int it) {
  const int tid = threadIdx.x, wv = tid >> 6, lane = tid & 63;
  const int b = blockIdx.x;
  const int dprev = done_arr[it];
  if (dprev) {                    // frozen: just propagate the chain
    if (b == 0 && tid == 0) { idx_arr[it + 1] = idx_arr[it]; done_arr[it + 1] = 1; }
    return;
  }
  __shared__ float zl[N];
  const int jbase = ((b & 7) << 8) + ((b >> 3) << 2);
  const int idx = idx_arr[it];
  {
    const float* __restrict__ zn = z_hist + (size_t)(it + 1) * N;
    *(float4*)&zl[tid * 8]     = *(const float4*)(zn + tid * 8);
    *(float4*)&zl[tid * 8 + 4] = *(const float4*)(zn + tid * 8 + 4);
  }
  __syncthreads();
  const int j = jbase + wv;
  const _Float16* __restrict__ Kc = KT + (size_t)j * N;
  float s = 0.f;
  #pragma unroll
  for (int p = 0; p < 4; ++p) {
    int i = lane * 8 + p * 512;
    h16x8 k8 = *(const h16x8*)(Kc + i);
    float4 za = *(const float4*)&zl[i];
    float4 zb = *(const float4*)&zl[i + 4];
    s += (float)k8[0] * za.x + (float)k8[1] * za.y
       + (float)k8[2] * za.z + (float)k8[3] * za.w
       + (float)k8[4] * zb.x + (float)k8[5] * zb.y
       + (float)k8[6] * zb.z + (float)k8[7] * zb.w;
  }
  s = wave_sum(s);
  if (lane == 0) {
    float wc = w_hist[(size_t)idx * N + j];
    float den = wc * s + 1e-6f;
    w_hist[(size_t)(it + 1) * N + j] = wc * MU / den;
  }
  if (b == 0) {   // block-uniform branch: err in u-domain + convergence chain
    const float* __restrict__ un = u_hist + (size_t)(it + 1) * N;
    const float* __restrict__ uc = u_hist + (size_t)idx * N;
    float e = 0.f;
    #pragma unroll
    for (int p = 0; p < 2; ++p) {
      int i = tid * 4 + p * 1024;
      float4 a = *(const float4*)(un + i);
      float4 c = *(const float4*)(uc + i);
      e += fabsf(a.x - c.x) + fabsf(a.y - c.y)
         + fabsf(a.z - c.z) + fabsf(a.w - c.w);
    }
    e = wave_sum(e);
    __shared__ float sh4[4];
    if (lane == 0) sh4[wv] = e;
    __syncthreads();
    if (tid == 0) {
      float err = (sh4[0] + sh4[1]) + (sh4[2] + sh4[3]);
      idx_arr[it + 1] = it + 1;
      done_arr[it + 1] = (err < TOL) ? 1 : 0;
    }
  }
}

// ---------------- loss: sum_i z_i sum_j K_ij * w_j * (-eps*log(K_ij)) ----------------
__global__ __launch_bounds__(512) void loss_pass(const _Float16* __restrict__ K,
    const float* __restrict__ z_hist, const float* __restrict__ w_hist,
    const int* __restrict__ idx_arr, float* __restrict__ losspart) {
  __shared__ float wl[N];
  __shared__ float sh8[8];
  const int tid = threadIdx.x, wv = tid >> 6, lane = tid & 63;
  const int b = blockIdx.x;
  const int rbase = ((b & 7) << 8) + ((b >> 3) << 3);
  const int idx = idx_arr[NITER];
  *(float4*)&wl[tid * 4] = *(const float4*)(w_hist + (size_t)idx * N + tid * 4);
  __syncthreads();
  const int r = rbase + wv;
  const _Float16* __restrict__ Krow = K + (size_t)r * N;
  float s = 0.f;
  #pragma unroll
  for (int p = 0; p < 4; ++p) {
    int j = lane * 8 + p * 512;
    h16x8 k8 = *(const h16x8*)(Krow + j);
    #pragma unroll
    for (int q = 0; q < 8; ++q) {
      float kf = (float)k8[q];
      s += kf * wl[j + q] * (-EPS * logf(kf));
    }
  }
  s = wave_sum(s);
  if (lane == 0) sh8[wv] = s * z_hist[(size_t)idx * N + r];
  __syncthreads();
  if (tid == 0)
    losspart[b] = ((sh8[0] + sh8[1]) + (sh8[2] + sh8[3]))
                + ((sh8[4] + sh8[5]) + (sh8[6] + sh8[7]));
}

__global__ __launch_bounds__(256) void loss_reduce(const float* __restrict__ losspart,
                                                   float* __restrict__ out) {
  float s = losspart[threadIdx.x];
  s = wave_sum(s);
  __shared__ float sh4[4];
  if ((threadIdx.x & 63) == 0) sh4[threadIdx.x >> 6] = s;
  __syncthreads();
  if (threadIdx.x == 0) out[0] = (sh4[0] + sh4[1]) + (sh4[2] + sh4[3]);
}

extern "C" void kernel_launch(void* const* d_in, const int* in_sizes, int n_in,
                              void* d_out, int out_size, void* d_ws, size_t ws_size,
                              hipStream_t stream) {
  const float* A = (const float*)d_in[0];
  const float* B = (const float*)d_in[1];
  float* out = (float*)d_out;

  char* base = (char*)d_ws;
  _Float16* K    = (_Float16*)base;                              // 8 MiB
  _Float16* KT   = (_Float16*)(base + (size_t)N * N * 2);        // 8 MiB
  float* z_hist  = (float*)(base + (size_t)2 * N * N * 2);       // [11][N]
  float* w_hist  = z_hist + (size_t)(NITER + 1) * N;
  float* u_hist  = w_hist + (size_t)(NITER + 1) * N;
  float* losspart= u_hist + (size_t)(NITER + 1) * N;             // [256]
  int*   idx_arr = (int*)(losspart + 256);                       // [11]
  int*   done_arr= idx_arr + (NITER + 1);                        // [11]

  build_k<<<1024, 256, 0, stream>>>(A, B, K, KT, z_hist, w_hist, u_hist,
                                    idx_arr, done_arr);
  for (int it = 0; it < NITER; ++it) {
    rowz<<<512, 256, 0, stream>>>(K, z_hist, w_hist, u_hist, idx_arr,
                                  done_arr, it);
    colw<<<512, 256, 0, stream>>>(KT, z_hist, w_hist, u_hist, idx_arr,
                                  done_arr, it);
  }
  loss_pass<<<256, 512, 0, stream>>>(K, z_hist, w_hist, idx_arr, losspart);
  loss_reduce<<<1, 256, 0, stream>>>(losspart, out);
}